// Round 1
// baseline (783.312 us; speedup 1.0000x reference)
//
#include <hip/hip_runtime.h>

#define D   42
#define ED  10
#define NU  16384
#define EU  32768
#define NV  20480
#define EV  40960
#define NT  (NU + NV)   // 36864
#define ET  (EU + EV)   // 73728
#define GJ  462         // 11 * 42 (10 h-channels + bias channel)
#define GS  512         // padded g row stride (floats)
#define STEPS 6

// ---------------- prep: build A [2][42][GS] (transposed en2_w + bias row), zero mean ----------
// A[phase][i][k*42+o] = en2_w[k, i*42+o]  (k<10);  A[phase][i][10*42+o] = en2_b[i*42+o]
__global__ void k_prep(const float* __restrict__ su_w2, const float* __restrict__ su_b2,
                       const float* __restrict__ sv_w2, const float* __restrict__ sv_b2,
                       float* __restrict__ A, float* __restrict__ mean) {
    int gid = blockIdx.x * 256 + threadIdx.x;
    if (gid < 128) mean[gid] = 0.f;
    if (gid >= 2 * D * GS) return;
    int phase = gid / (D * GS);
    int r = gid - phase * D * GS;
    int i = r / GS, j = r - i * GS;
    const float* w2 = phase ? sv_w2 : su_w2;
    const float* b2 = phase ? sv_b2 : su_b2;
    float v = 0.f;
    if (j < GJ) {
        int k = j / D, o = j - k * D;
        v = (k < ED) ? w2[k * (D * D) + i * D + o] : b2[i * D + o];
    }
    A[gid] = v;
}

// ---------------- lin0: out = relu(x @ lw + lb) --------------------------------------------
__global__ void k_lin0(const float* __restrict__ su_x, const float* __restrict__ sv_x,
                       const float* __restrict__ su_w, const float* __restrict__ su_b,
                       const float* __restrict__ sv_w, const float* __restrict__ sv_b,
                       float* __restrict__ out) {
    int gid = blockIdx.x * 256 + threadIdx.x;
    if (gid >= NT * D) return;
    int n = gid / D, o = gid - n * D;
    const float *x, *w, *b; int nl;
    if (n < NU) { x = su_x; w = su_w; b = su_b; nl = n; }
    else        { x = sv_x; w = sv_w; b = sv_b; nl = n - NU; }
    float s = b[o];
    #pragma unroll
    for (int i = 0; i < D; i++) s += x[nl * D + i] * w[i * D + o];
    out[gid] = fmaxf(s, 0.f);
}

// ---------------- edge h: h[e,k]=relu(ef@en1_w+en1_b), h[e,10]=1 ----------------------------
__global__ void k_edgeh(const float* __restrict__ su_e, const float* __restrict__ sv_e,
                        const float* __restrict__ su_w1, const float* __restrict__ su_b1,
                        const float* __restrict__ sv_w1, const float* __restrict__ sv_b1,
                        float* __restrict__ h) {
    __shared__ float w1s[2][ED * ED];
    __shared__ float b1s[2][ED];
    int tid = threadIdx.x;
    if (tid < ED * ED) { w1s[0][tid] = su_w1[tid]; w1s[1][tid] = sv_w1[tid]; }
    if (tid < ED)      { b1s[0][tid] = su_b1[tid]; b1s[1][tid] = sv_b1[tid]; }
    __syncthreads();
    int e = blockIdx.x * 256 + tid;
    if (e >= ET) return;
    int ph = (e >= EU);
    const float* ef = ph ? (sv_e + (size_t)(e - EU) * ED) : (su_e + (size_t)e * ED);
    float v[ED];
    #pragma unroll
    for (int j = 0; j < ED; j++) v[j] = ef[j];
    #pragma unroll
    for (int k = 0; k < ED; k++) {
        float s = b1s[ph][k];
        #pragma unroll
        for (int j = 0; j < ED; j++) s += v[j] * w1s[ph][j * ED + k];
        h[e * 12 + k] = fmaxf(s, 0.f);
    }
    h[e * 12 + 10] = 1.f;
    h[e * 12 + 11] = 0.f;
}

// ---------------- g GEMM: g[n, j] = sum_i out[n,i] * A[i,j]; also zero agg ------------------
// block: 512 threads = 128 j-threads (x4 floats) * 4 n-threads (x8 nodes); 32 nodes/block
__global__ __launch_bounds__(512, 1) void k_g(const float* __restrict__ out,
                                              const float* __restrict__ A,
                                              float* __restrict__ g,
                                              float* __restrict__ agg) {
    __shared__ float As[D * GS];      // 84 KB
    __shared__ float outT[D * 36];    // 42 rows, stride 36 floats (32 nodes + pad)
    int tid = threadIdx.x;
    int n0 = blockIdx.x * 32;
    const float4* Ag = (const float4*)(A + (n0 >= NU ? D * GS : 0));
    float4* As4 = (float4*)As;
    for (int idx = tid; idx < D * GS / 4; idx += 512) As4[idx] = Ag[idx];
    for (int idx = tid; idx < 32 * D; idx += 512) {
        int nn = idx / D, i = idx - nn * D;
        outT[i * 36 + nn] = out[(size_t)(n0 + nn) * D + i];
    }
    for (int idx = tid; idx < 32 * D; idx += 512) agg[(size_t)n0 * D + idx] = 0.f;
    __syncthreads();

    int tj = tid & 127;          // j-group: 4 floats at j = 4*tj
    int tn = tid >> 7;           // node-group: nodes n0 + 8*tn .. +7  (uniform per wave)
    float4 acc[8];
    #pragma unroll
    for (int r = 0; r < 8; r++) acc[r] = make_float4(0.f, 0.f, 0.f, 0.f);
    const float4* outT4 = (const float4*)outT;

    for (int i = 0; i < D; i++) {
        float4 a  = As4[i * (GS / 4) + tj];
        float4 o0 = outT4[i * 9 + tn * 2];
        float4 o1 = outT4[i * 9 + tn * 2 + 1];
#define MAC(rr, ov) acc[rr].x += a.x * (ov); acc[rr].y += a.y * (ov); \
                    acc[rr].z += a.z * (ov); acc[rr].w += a.w * (ov);
        MAC(0, o0.x) MAC(1, o0.y) MAC(2, o0.z) MAC(3, o0.w)
        MAC(4, o1.x) MAC(5, o1.y) MAC(6, o1.z) MAC(7, o1.w)
#undef MAC
    }
    float4* g4 = (float4*)g;
    #pragma unroll
    for (int r = 0; r < 8; r++) {
        int n = n0 + tn * 8 + r;
        g4[(size_t)n * (GS / 4) + tj] = acc[r];
    }
}

// ---------------- edge msg + scatter: agg[dst,o] += sum_k h[e,k]*g[src,k*42+o] --------------
__global__ void k_edge(const float* __restrict__ g, const float* __restrict__ h,
                       const int* __restrict__ su_src, const int* __restrict__ su_dst,
                       const int* __restrict__ sv_src, const int* __restrict__ sv_dst,
                       float* __restrict__ agg) {
    int gid = blockIdx.x * 256 + threadIdx.x;
    if (gid >= ET * D) return;
    int e = gid / D, o = gid - e * D;
    int src, dst;
    if (e < EU) { src = su_src[e];           dst = su_dst[e]; }
    else        { src = sv_src[e - EU] + NU; dst = sv_dst[e - EU] + NU; }
    const float* grow = g + (size_t)src * GS;
    const float* hrow = h + (size_t)e * 12;
    float s = 0.f;
    #pragma unroll
    for (int k = 0; k <= ED; k++) s += hrow[k] * grow[k * D + o];
    atomicAdd(&agg[(size_t)dst * D + o], s);
}

// ---------------- node update: m=relu(agg+out+cb); out=relu(m@mw+mb) ------------------------
__global__ void k_update(const float* __restrict__ agg, float* __restrict__ out,
                         const float* __restrict__ su_mw, const float* __restrict__ su_mb,
                         const float* __restrict__ su_cb,
                         const float* __restrict__ sv_mw, const float* __restrict__ sv_mb,
                         const float* __restrict__ sv_cb) {
    __shared__ float mws[D * D];
    __shared__ float mloc[32 * D];
    int tid = threadIdx.x;
    int n0 = blockIdx.x * 32;
    int ph = (n0 >= NU);
    const float* mw = ph ? sv_mw : su_mw;
    const float* mb = ph ? sv_mb : su_mb;
    const float* cb = ph ? sv_cb : su_cb;
    for (int idx = tid; idx < D * D; idx += 256) mws[idx] = mw[idx];
    for (int idx = tid; idx < 32 * D; idx += 256) {
        float v = agg[(size_t)n0 * D + idx] + out[(size_t)n0 * D + idx] + cb[idx % D];
        mloc[idx] = fmaxf(v, 0.f);
    }
    __syncthreads();
    for (int idx = tid; idx < 32 * D; idx += 256) {
        int nn = idx / D, o = idx - nn * D;
        float s = mb[o];
        #pragma unroll
        for (int i = 0; i < D; i++) s += mloc[nn * D + i] * mws[i * D + o];
        out[(size_t)n0 * D + idx] = fmaxf(s, 0.f);
    }
}

// ---------------- reduce: mean[ph*42+o] += sum_n (out[n,o] + x[n,o]) ------------------------
__global__ void k_reduce(const float* __restrict__ out, const float* __restrict__ su_x,
                         const float* __restrict__ sv_x, float* __restrict__ mean) {
    __shared__ float sdata[6 * D];
    int tid = threadIdx.x;
    int bid = blockIdx.x;
    int n0, ph, nl0;
    const float* x;
    if (bid < NU / 128) { ph = 0; n0 = bid * 128;               nl0 = n0;      x = su_x; }
    else                { ph = 1; n0 = NU + (bid - NU/128)*128; nl0 = n0 - NU; x = sv_x; }
    if (tid < 6 * D) {
        int o = tid % D, r = tid / D;
        float acc = 0.f;
        for (int nn = r; nn < 128; nn += 6)
            acc += out[(size_t)(n0 + nn) * D + o] + x[(size_t)(nl0 + nn) * D + o];
        sdata[r * D + o] = acc;
    }
    __syncthreads();
    if (tid < D) {
        float tot = 0.f;
        #pragma unroll
        for (int r = 0; r < 6; r++) tot += sdata[r * D + tid];
        atomicAdd(&mean[ph * D + tid], tot);
    }
}

// ---------------- final MLP --------------------------------------------------------------
__global__ void k_mlp(const float* __restrict__ mean,
                      const float* __restrict__ fc1w, const float* __restrict__ fc1b,
                      const float* __restrict__ fc2w, const float* __restrict__ fc2b,
                      const float* __restrict__ fc3w, const float* __restrict__ fc3b,
                      float* __restrict__ outp) {
    __shared__ float c[4 * D];
    __shared__ float h1[256];
    __shared__ float h2[128];
    int t = threadIdx.x;
    if (t < 4 * D) {
        float v;
        if (t < 2 * D) v = mean[t < D ? t : t - D] * (1.f / NU);
        else { int q = t - 2 * D; v = mean[D + (q < D ? q : q - D)] * (1.f / NV); }
        c[t] = v;
    }
    __syncthreads();
    float s = fc1b[t];
    for (int j = 0; j < 4 * D; j++) s += c[j] * fc1w[j * 256 + t];
    h1[t] = fmaxf(s, 0.f);
    __syncthreads();
    if (t < 128) {
        float s2 = fc2b[t];
        for (int j = 0; j < 256; j++) s2 += h1[j] * fc2w[j * 128 + t];
        h2[t] = fmaxf(s2, 0.f);
    }
    __syncthreads();
    if (t == 0) {
        float s3 = fc3b[0];
        for (int j = 0; j < 128; j++) s3 += h2[j] * fc3w[j];
        outp[0] = s3;
    }
}

extern "C" void kernel_launch(void* const* d_in, const int* in_sizes, int n_in,
                              void* d_out, int out_size, void* d_ws, size_t ws_size,
                              hipStream_t stream) {
    const float* su_x     = (const float*)d_in[0];
    const float* su_e     = (const float*)d_in[1];
    const int*   su_src   = (const int*)d_in[2];
    const int*   su_dst   = (const int*)d_in[3];
    const float* sv_x     = (const float*)d_in[4];
    const float* sv_e     = (const float*)d_in[5];
    const int*   sv_src   = (const int*)d_in[6];
    const int*   sv_dst   = (const int*)d_in[7];
    const float* su_lin0w = (const float*)d_in[8];
    const float* su_lin0b = (const float*)d_in[9];
    const float* su_msgw  = (const float*)d_in[10];
    const float* su_msgb  = (const float*)d_in[11];
    const float* su_en1w  = (const float*)d_in[12];
    const float* su_en1b  = (const float*)d_in[13];
    const float* su_en2w  = (const float*)d_in[14];
    const float* su_en2b  = (const float*)d_in[15];
    const float* su_convb = (const float*)d_in[16];
    const float* sv_lin0w = (const float*)d_in[17];
    const float* sv_lin0b = (const float*)d_in[18];
    const float* sv_msgw  = (const float*)d_in[19];
    const float* sv_msgb  = (const float*)d_in[20];
    const float* sv_en1w  = (const float*)d_in[21];
    const float* sv_en1b  = (const float*)d_in[22];
    const float* sv_en2w  = (const float*)d_in[23];
    const float* sv_en2b  = (const float*)d_in[24];
    const float* sv_convb = (const float*)d_in[25];
    const float* fc1w     = (const float*)d_in[26];
    const float* fc1b     = (const float*)d_in[27];
    const float* fc2w     = (const float*)d_in[28];
    const float* fc2b     = (const float*)d_in[29];
    const float* fc3w     = (const float*)d_in[30];
    const float* fc3b     = (const float*)d_in[31];

    float* ws   = (float*)d_ws;
    float* out  = ws;                          // NT*D
    float* g    = out  + (size_t)NT * D;       // NT*GS
    float* h    = g    + (size_t)NT * GS;      // ET*12
    float* agg  = h    + (size_t)ET * 12;      // NT*D
    float* A    = agg  + (size_t)NT * D;       // 2*D*GS
    float* mean = A    + (size_t)2 * D * GS;   // 128
    // total ws use: ~91.6 MB

    // zero pred slot + the 16384x20480 interaction output (all zeros)
    hipMemsetAsync(d_out, 0, (size_t)out_size * sizeof(float), stream);

    k_prep<<<(2 * D * GS + 255) / 256, 256, 0, stream>>>(su_en2w, su_en2b, sv_en2w, sv_en2b, A, mean);
    k_lin0<<<(NT * D + 255) / 256, 256, 0, stream>>>(su_x, sv_x, su_lin0w, su_lin0b, sv_lin0w, sv_lin0b, out);
    k_edgeh<<<(ET + 255) / 256, 256, 0, stream>>>(su_e, sv_e, su_en1w, su_en1b, sv_en1w, sv_en1b, h);

    for (int s = 0; s < STEPS; s++) {
        k_g<<<NT / 32, 512, 0, stream>>>(out, A, g, agg);
        k_edge<<<(ET * D + 255) / 256, 256, 0, stream>>>(g, h, su_src, su_dst, sv_src, sv_dst, agg);
        k_update<<<NT / 32, 256, 0, stream>>>(agg, out, su_msgw, su_msgb, su_convb,
                                              sv_msgw, sv_msgb, sv_convb);
    }

    k_reduce<<<NU / 128 + NV / 128, 256, 0, stream>>>(out, su_x, sv_x, mean);
    k_mlp<<<1, 256, 0, stream>>>(mean, fc1w, fc1b, fc2w, fc2b, fc3w, fc3b, (float*)d_out);
}